// Round 11
// baseline (593.734 us; speedup 1.0000x reference)
//
#include <hip/hip_runtime.h>
#include <hip/hip_bf16.h>

// GATv2 x3 layers, MI355X. f32 in/out; edge_index int32.
// R11: k_score writes w=exp(score) (no-max softmax — scores bounded, clamped
// +-60), 16-channel superblocks with 8 loads in flight, XCD-swizzled blocks
// for dst L2 locality. k_agg single pass (no max/exp). 1024-thread scan.

#define NN 10000    // nodes
#define NE 200000   // edges
#define ND 128      // node dim (layer 0 input)
#define ED 16       // edge dim
#define CD 64       // conv dim (per head)
#define NH 5        // heads
#define HC 320      // NH*CD
#define EF 210000   // NE + NN (with self loops)
#define EFP 210048  // EF padded to 64
#define NEG 0.2f
#define SB 103      // k_score blocks per XCD slice (824 = 8*103 blocks)

// ---- CSR build: count ----
__global__ void k_count(const int* __restrict__ dst, int* __restrict__ deg) {
  int e = blockIdx.x * blockDim.x + threadIdx.x;
  if (e >= NE) return;
  atomicAdd(&deg[dst[e]], 1);
}

// ---- CSR build: exclusive scan (single block, 1024 threads x 10 elems) ----
__global__ __launch_bounds__(1024) void k_scan(const int* __restrict__ deg,
                                               int* __restrict__ rowptr) {
  __shared__ int part[1024];
  int t = threadIdx.x;
  int base = t * 10;
  int local[10];
  int s = 0;
  #pragma unroll
  for (int j = 0; j < 10; j++) {
    int i = base + j;
    local[j] = (i < NN) ? deg[i] : 0;
    s += local[j];
  }
  part[t] = s;
  __syncthreads();
  for (int off = 1; off < 1024; off <<= 1) {
    int v = (t >= off) ? part[t - off] : 0;
    __syncthreads();
    part[t] += v;
    __syncthreads();
  }
  int prefix = (t > 0) ? part[t - 1] : 0;
  #pragma unroll
  for (int j = 0; j < 10; j++) {
    int i = base + j;
    if (i < NN) rowptr[i] = prefix;
    prefix += local[j];
  }
  if (t == 1023) rowptr[NN] = prefix;
}

// ---- CSR build: fill ----
__global__ void k_fill(const int* __restrict__ ei, const int* __restrict__ rowptr,
                       int* __restrict__ cursor, int* __restrict__ csr_eid,
                       int* __restrict__ csr_src, int* __restrict__ csr_dst) {
  int e = blockIdx.x * blockDim.x + threadIdx.x;
  if (e >= NE) return;
  int d = ei[NE + e];
  int slot = atomicAdd(&cursor[d], 1);
  int pos = rowptr[d] + slot;
  csr_eid[pos] = e;
  csr_src[pos] = ei[e];
  csr_dst[pos] = d;
}

// ---- loop_attr = mean of incoming edge_attr (gather, wave per node) ----
__global__ __launch_bounds__(256) void k_loopattr(const int* __restrict__ csr_eid,
                                                  const int* __restrict__ rowptr,
                                                  const float* __restrict__ eattr,
                                                  float* __restrict__ loop_attr) {
  int wave = threadIdx.x >> 6, lane = threadIdx.x & 63;
  int d = blockIdx.x * 4 + wave;
  if (d >= NN) return;
  int g = lane >> 4, k = lane & 15;
  int b = rowptr[d], n = rowptr[d + 1] - b;
  float s = 0.f;
  for (int i = g; i < n; i += 4)
    s += eattr[(size_t)csr_eid[b + i] * ED + k];
  s += __shfl_xor(s, 16, 64);
  s += __shfl_xor(s, 32, 64);
  if (g == 0) loop_attr[d * ED + k] = s / fmaxf((float)n, 1.0f);
}

// ---- ea_csr[p] = edge attrs permuted into CSR order (real edges only) ----
__global__ void k_eacsr(const int* __restrict__ csr_eid, const float* __restrict__ eattr,
                        float* __restrict__ ea_csr) {
  int idx = blockIdx.x * blockDim.x + threadIdx.x;  // (p, quad)
  if (idx >= NE * 4) return;
  int p = idx >> 2, q = idx & 3;
  const float4* sp = (const float4*)(eattr + (size_t)csr_eid[p] * ED);
  ((float4*)(ea_csr + (size_t)p * ED))[q] = sp[q];
}

// ---- WeT[hc][k] = We[k][hc]  (tiny per-layer transpose) ----
__global__ void k_wet(const float* __restrict__ We, float* __restrict__ WeT) {
  int i = blockIdx.x * blockDim.x + threadIdx.x;  // i = hc*ED + k
  if (i >= ED * HC) return;
  int hc = i >> 4, k = i & 15;
  WeT[i] = We[k * HC + hc];
}

// ---- xl = h @ Wl + bl  (no LDS; h rows via uniform broadcast loads) ----
template <int D>
__global__ __launch_bounds__(320) void k_xl(const float* __restrict__ h,
                                            const float* __restrict__ Wl,
                                            const float* __restrict__ bl,
                                            float* __restrict__ xl) {
  constexpr int NPB = 8;
  int node0 = blockIdx.x * NPB;
  int t = threadIdx.x;  // output column 0..319
  float acc[NPB];
  #pragma unroll
  for (int i = 0; i < NPB; i++) acc[i] = 0.f;
  for (int k = 0; k < D; k += 4) {
    float w0 = Wl[(k + 0) * HC + t];
    float w1 = Wl[(k + 1) * HC + t];
    float w2 = Wl[(k + 2) * HC + t];
    float w3 = Wl[(k + 3) * HC + t];
    #pragma unroll
    for (int i = 0; i < NPB; i++) {
      float4 hv = *(const float4*)(h + (size_t)(node0 + i) * D + k);
      acc[i] += hv.x * w0 + hv.y * w1 + hv.z * w2 + hv.w * w3;
    }
  }
  float bv = bl[t];
  #pragma unroll
  for (int i = 0; i < NPB; i++)
    xl[(size_t)(node0 + i) * HC + t] = acc[i] + bv;
}

__device__ __forceinline__ float dot4(float4 a, float4 b) {
  return a.x * b.x + a.y * b.y + a.z * b.z + a.w * b.w;
}

// ---- scores: ONE THREAD PER (EDGE, HEAD); writes w = exp(clamped score).
// 16-channel superblocks: 8 float4 loads issued up-front per block.
// XCD swizzle: contiguous CSR slice per XCD -> dst rows L2-resident.
__global__ __launch_bounds__(256) void k_score(
    const int* __restrict__ csr_src, const int* __restrict__ csr_dst,
    const float* __restrict__ ea_csr, const float* __restrict__ loop_attr,
    const float* __restrict__ xl, const float* __restrict__ WeT,
    const float* __restrict__ att, float* __restrict__ wP) {
  int bid = blockIdx.x;                       // 0..8*SB-1
  int lb = (bid & 7) * SB + (bid >> 3);       // contiguous slice per XCD
  int p = lb * 256 + threadIdx.x;
  if (p >= EF) return;
  int h = blockIdx.y;
  int s, d;
  const float* ea;
  if (p < NE) { s = csr_src[p]; d = csr_dst[p]; ea = ea_csr + (size_t)p * ED; }
  else        { s = d = p - NE; ea = loop_attr + (size_t)(p - NE) * ED; }
  float4 ea4[4];
  {
    const float4* q = (const float4*)ea;
    ea4[0] = q[0]; ea4[1] = q[1]; ea4[2] = q[2]; ea4[3] = q[3];
  }
  const float* xsrow = xl + (size_t)s * HC + h * CD;
  const float* xdrow = xl + (size_t)d * HC + h * CD;
  const float* wrow  = WeT + h * CD * ED;
  const float* arow  = att + h * CD;
  float sc = 0.f;
  #pragma unroll
  for (int cb = 0; cb < CD; cb += 16) {  // 4 superblocks
    float4 xs[4], xd[4];
    #pragma unroll
    for (int j = 0; j < 4; j++) {
      xs[j] = *(const float4*)(xsrow + cb + 4 * j);
      xd[j] = *(const float4*)(xdrow + cb + 4 * j);
    }
    #pragma unroll
    for (int j = 0; j < 4; j++) {
      int c = cb + 4 * j;
      const float4* w0 = (const float4*)(wrow + (c + 0) * ED);
      const float4* w1 = (const float4*)(wrow + (c + 1) * ED);
      const float4* w2 = (const float4*)(wrow + (c + 2) * ED);
      const float4* w3 = (const float4*)(wrow + (c + 3) * ED);
      float z0 = xs[j].x + xd[j].x + dot4(ea4[0], w0[0]) + dot4(ea4[1], w0[1]) +
                 dot4(ea4[2], w0[2]) + dot4(ea4[3], w0[3]);
      float z1 = xs[j].y + xd[j].y + dot4(ea4[0], w1[0]) + dot4(ea4[1], w1[1]) +
                 dot4(ea4[2], w1[2]) + dot4(ea4[3], w1[3]);
      float z2 = xs[j].z + xd[j].z + dot4(ea4[0], w2[0]) + dot4(ea4[1], w2[1]) +
                 dot4(ea4[2], w2[2]) + dot4(ea4[3], w2[3]);
      float z3 = xs[j].w + xd[j].w + dot4(ea4[0], w3[0]) + dot4(ea4[1], w3[1]) +
                 dot4(ea4[2], w3[2]) + dot4(ea4[3], w3[3]);
      z0 *= (z0 > 0.f) ? 1.0f : NEG;
      z1 *= (z1 > 0.f) ? 1.0f : NEG;
      z2 *= (z2 > 0.f) ? 1.0f : NEG;
      z3 *= (z3 > 0.f) ? 1.0f : NEG;
      float4 a4 = *(const float4*)(arow + c);
      sc += a4.x * z0 + a4.y * z1 + a4.z * z2 + a4.w * z3;
    }
  }
  sc = fminf(fmaxf(sc, -60.f), 60.f);  // clamp never binds for sane inputs
  wP[(size_t)h * EFP + p] = __expf(sc);
}

// ---- aggregation: block per node, wave per head; single pass (no max/exp) --
__global__ __launch_bounds__(320) void k_agg(
    const int* __restrict__ csr_src, const int* __restrict__ rowptr,
    const float* __restrict__ wP, const float* __restrict__ xl,
    const float* __restrict__ bias, float* __restrict__ out) {
  __shared__ float s_v[NH][CD];
  int h = threadIdx.x >> 6, lane = threadIdx.x & 63;
  int d = blockIdx.x;
  int b = rowptr[d], n = rowptr[d + 1] - b;
  const float* sp = wP + (size_t)h * EFP;
  const float* xlh = xl + h * CD + lane;
  // self loop init
  float dn = sp[NE + d];
  float acc = dn * xlh[(size_t)d * HC];
  // edge loop, unroll 4 (uniform w addrs -> scalar loads)
  int p = b, pe = b + n;
  for (; p + 4 <= pe; p += 4) {
    int s0 = csr_src[p], s1 = csr_src[p + 1], s2 = csr_src[p + 2], s3 = csr_src[p + 3];
    float w0 = sp[p], w1 = sp[p + 1], w2 = sp[p + 2], w3 = sp[p + 3];
    float x0 = xlh[(size_t)s0 * HC];
    float x1 = xlh[(size_t)s1 * HC];
    float x2 = xlh[(size_t)s2 * HC];
    float x3 = xlh[(size_t)s3 * HC];
    dn += (w0 + w1) + (w2 + w3);
    acc += w0 * x0 + w1 * x1 + w2 * x2 + w3 * x3;
  }
  for (; p < pe; p++) {
    int s0 = csr_src[p];
    float w0 = sp[p];
    dn += w0;
    acc += w0 * xlh[(size_t)s0 * HC];
  }
  s_v[h][lane] = acc / dn;
  __syncthreads();
  if (h == 0) {
    float v = s_v[0][lane] + s_v[1][lane] + s_v[2][lane] + s_v[3][lane] + s_v[4][lane];
    v = v * (1.0f / NH) + bias[lane];
    v = v > 0.f ? v : expm1f(v);
    out[(size_t)d * CD + lane] = v;
  }
}

extern "C" void kernel_launch(void* const* d_in, const int* in_sizes, int n_in,
                              void* d_out, int out_size, void* d_ws, size_t ws_size,
                              hipStream_t stream) {
  const float* x = (const float*)d_in[0];
  const int* ei = (const int*)d_in[1];      // [2, NE]: src row then dst row
  const float* eattr = (const float*)d_in[2];

  char* w = (char*)d_ws;
  int* degi      = (int*)w;                 w += NN * 4;
  int* cursor    = (int*)w;                 w += NN * 4;
  int* rowptr    = (int*)w;                 w += (NN + 1) * 4;
  int* csr_eid   = (int*)w;                 w += NE * 4;
  int* csr_src   = (int*)w;                 w += NE * 4;
  int* csr_dst   = (int*)w;                 w += NE * 4;
  float* loop_attr = (float*)w;             w += (size_t)NN * ED * 4;
  float* ea_csr  = (float*)w;               w += (size_t)NE * ED * 4;
  float* xl      = (float*)w;               w += (size_t)NN * HC * 4;
  float* wPbuf   = (float*)w;               w += (size_t)NH * EFP * 4;
  float* WeT     = (float*)w;               w += (size_t)ED * HC * 4;
  float* hbuf    = (float*)w;               w += (size_t)NN * CD * 4;

  // graph structure + permuted edge attrs (layer-invariant)
  hipMemsetAsync(degi, 0, NN * 4, stream);
  hipMemsetAsync(cursor, 0, NN * 4, stream);
  k_count<<<(NE + 255) / 256, 256, 0, stream>>>(ei + NE, degi);
  k_scan<<<1, 1024, 0, stream>>>(degi, rowptr);
  k_fill<<<(NE + 255) / 256, 256, 0, stream>>>(ei, rowptr, cursor, csr_eid, csr_src, csr_dst);
  k_loopattr<<<(NN + 3) / 4, 256, 0, stream>>>(csr_eid, rowptr, eattr, loop_attr);
  k_eacsr<<<(NE * 4 + 255) / 256, 256, 0, stream>>>(csr_eid, eattr, ea_csr);

  for (int l = 0; l < 3; l++) {
    const float* Wl  = (const float*)d_in[3 + 5 * l];
    const float* bl  = (const float*)d_in[4 + 5 * l];
    const float* We  = (const float*)d_in[5 + 5 * l];
    const float* att = (const float*)d_in[6 + 5 * l];
    const float* b   = (const float*)d_in[7 + 5 * l];

    k_wet<<<(ED * HC + 255) / 256, 256, 0, stream>>>(We, WeT);
    if (l == 0) k_xl<ND><<<NN / 8, 320, 0, stream>>>(x, Wl, bl, xl);
    else        k_xl<CD><<<NN / 8, 320, 0, stream>>>(hbuf, Wl, bl, xl);

    dim3 gs(8 * SB, NH);
    k_score<<<gs, 256, 0, stream>>>(csr_src, csr_dst, ea_csr, loop_attr,
                                    xl, WeT, att, wPbuf);

    float* dst_out = (l < 2) ? hbuf : (float*)d_out;
    k_agg<<<NN, 320, 0, stream>>>(csr_src, rowptr, wPbuf, xl, b, dst_out);
  }
}

// Round 12
// 528.664 us; speedup vs baseline: 1.1231x; 1.1231x over previous
//
#include <hip/hip_runtime.h>
#include <hip/hip_bf16.h>

// GATv2 x3 layers, MI355X. f32 in/out; edge_index int32.
// R12: R10's k_score loop body (VGPR=64 codegen, 74us — R11's superblock
// rewrite made the compiler serialize loads at VGPR=36, 96us) + R11's
// exp-in-score (no-max softmax) + XCD swizzle + single-pass k_agg + fast scan.

#define NN 10000    // nodes
#define NE 200000   // edges
#define ND 128      // node dim (layer 0 input)
#define ED 16       // edge dim
#define CD 64       // conv dim (per head)
#define NH 5        // heads
#define HC 320      // NH*CD
#define EF 210000   // NE + NN (with self loops)
#define EFP 210048  // EF padded to 64
#define NEG 0.2f
#define SB 103      // k_score blocks per XCD slice (824 = 8*103 blocks)

// ---- CSR build: count ----
__global__ void k_count(const int* __restrict__ dst, int* __restrict__ deg) {
  int e = blockIdx.x * blockDim.x + threadIdx.x;
  if (e >= NE) return;
  atomicAdd(&deg[dst[e]], 1);
}

// ---- CSR build: exclusive scan (single block, 1024 threads x 10 elems) ----
__global__ __launch_bounds__(1024) void k_scan(const int* __restrict__ deg,
                                               int* __restrict__ rowptr) {
  __shared__ int part[1024];
  int t = threadIdx.x;
  int base = t * 10;
  int local[10];
  int s = 0;
  #pragma unroll
  for (int j = 0; j < 10; j++) {
    int i = base + j;
    local[j] = (i < NN) ? deg[i] : 0;
    s += local[j];
  }
  part[t] = s;
  __syncthreads();
  for (int off = 1; off < 1024; off <<= 1) {
    int v = (t >= off) ? part[t - off] : 0;
    __syncthreads();
    part[t] += v;
    __syncthreads();
  }
  int prefix = (t > 0) ? part[t - 1] : 0;
  #pragma unroll
  for (int j = 0; j < 10; j++) {
    int i = base + j;
    if (i < NN) rowptr[i] = prefix;
    prefix += local[j];
  }
  if (t == 1023) rowptr[NN] = prefix;
}

// ---- CSR build: fill ----
__global__ void k_fill(const int* __restrict__ ei, const int* __restrict__ rowptr,
                       int* __restrict__ cursor, int* __restrict__ csr_eid,
                       int* __restrict__ csr_src, int* __restrict__ csr_dst) {
  int e = blockIdx.x * blockDim.x + threadIdx.x;
  if (e >= NE) return;
  int d = ei[NE + e];
  int slot = atomicAdd(&cursor[d], 1);
  int pos = rowptr[d] + slot;
  csr_eid[pos] = e;
  csr_src[pos] = ei[e];
  csr_dst[pos] = d;
}

// ---- loop_attr = mean of incoming edge_attr (gather, wave per node) ----
__global__ __launch_bounds__(256) void k_loopattr(const int* __restrict__ csr_eid,
                                                  const int* __restrict__ rowptr,
                                                  const float* __restrict__ eattr,
                                                  float* __restrict__ loop_attr) {
  int wave = threadIdx.x >> 6, lane = threadIdx.x & 63;
  int d = blockIdx.x * 4 + wave;
  if (d >= NN) return;
  int g = lane >> 4, k = lane & 15;
  int b = rowptr[d], n = rowptr[d + 1] - b;
  float s = 0.f;
  for (int i = g; i < n; i += 4)
    s += eattr[(size_t)csr_eid[b + i] * ED + k];
  s += __shfl_xor(s, 16, 64);
  s += __shfl_xor(s, 32, 64);
  if (g == 0) loop_attr[d * ED + k] = s / fmaxf((float)n, 1.0f);
}

// ---- ea_csr[p] = edge attrs permuted into CSR order (real edges only) ----
__global__ void k_eacsr(const int* __restrict__ csr_eid, const float* __restrict__ eattr,
                        float* __restrict__ ea_csr) {
  int idx = blockIdx.x * blockDim.x + threadIdx.x;  // (p, quad)
  if (idx >= NE * 4) return;
  int p = idx >> 2, q = idx & 3;
  const float4* sp = (const float4*)(eattr + (size_t)csr_eid[p] * ED);
  ((float4*)(ea_csr + (size_t)p * ED))[q] = sp[q];
}

// ---- WeT[hc][k] = We[k][hc]  (tiny per-layer transpose) ----
__global__ void k_wet(const float* __restrict__ We, float* __restrict__ WeT) {
  int i = blockIdx.x * blockDim.x + threadIdx.x;  // i = hc*ED + k
  if (i >= ED * HC) return;
  int hc = i >> 4, k = i & 15;
  WeT[i] = We[k * HC + hc];
}

// ---- xl = h @ Wl + bl  (no LDS; h rows via uniform broadcast loads) ----
template <int D>
__global__ __launch_bounds__(320) void k_xl(const float* __restrict__ h,
                                            const float* __restrict__ Wl,
                                            const float* __restrict__ bl,
                                            float* __restrict__ xl) {
  constexpr int NPB = 8;
  int node0 = blockIdx.x * NPB;
  int t = threadIdx.x;  // output column 0..319
  float acc[NPB];
  #pragma unroll
  for (int i = 0; i < NPB; i++) acc[i] = 0.f;
  for (int k = 0; k < D; k += 4) {
    float w0 = Wl[(k + 0) * HC + t];
    float w1 = Wl[(k + 1) * HC + t];
    float w2 = Wl[(k + 2) * HC + t];
    float w3 = Wl[(k + 3) * HC + t];
    #pragma unroll
    for (int i = 0; i < NPB; i++) {
      float4 hv = *(const float4*)(h + (size_t)(node0 + i) * D + k);
      acc[i] += hv.x * w0 + hv.y * w1 + hv.z * w2 + hv.w * w3;
    }
  }
  float bv = bl[t];
  #pragma unroll
  for (int i = 0; i < NPB; i++)
    xl[(size_t)(node0 + i) * HC + t] = acc[i] + bv;
}

__device__ __forceinline__ float dot4(float4 a, float4 b) {
  return a.x * b.x + a.y * b.y + a.z * b.z + a.w * b.w;
}

// ---- scores: ONE THREAD PER (EDGE, HEAD); writes w = exp(clamped score).
// R10 loop body (unroll 4, 2 loads/iter -> VGPR~64, loads pipelined).
// XCD swizzle: contiguous CSR slice per XCD -> dst rows L2-resident.
__global__ __launch_bounds__(256) void k_score(
    const int* __restrict__ csr_src, const int* __restrict__ csr_dst,
    const float* __restrict__ ea_csr, const float* __restrict__ loop_attr,
    const float* __restrict__ xl, const float* __restrict__ WeT,
    const float* __restrict__ att, float* __restrict__ wP) {
  int bid = blockIdx.x;                       // 0..8*SB-1
  int lb = (bid & 7) * SB + (bid >> 3);       // contiguous slice per XCD
  int p = lb * 256 + threadIdx.x;
  if (p >= EF) return;
  int h = blockIdx.y;
  int s, d;
  const float* ea;
  if (p < NE) { s = csr_src[p]; d = csr_dst[p]; ea = ea_csr + (size_t)p * ED; }
  else        { s = d = p - NE; ea = loop_attr + (size_t)(p - NE) * ED; }
  float4 ea4[4];
  {
    const float4* q = (const float4*)ea;
    ea4[0] = q[0]; ea4[1] = q[1]; ea4[2] = q[2]; ea4[3] = q[3];
  }
  const float* xsrow = xl + (size_t)s * HC + h * CD;
  const float* xdrow = xl + (size_t)d * HC + h * CD;
  const float* wrow  = WeT + h * CD * ED;
  const float* arow  = att + h * CD;
  float sc = 0.f;
  #pragma unroll 4
  for (int cb = 0; cb < CD; cb += 4) {  // 16 iterations
    float4 xs4 = *(const float4*)(xsrow + cb);
    float4 xd4 = *(const float4*)(xdrow + cb);
    const float4* w0 = (const float4*)(wrow + (cb + 0) * ED);
    const float4* w1 = (const float4*)(wrow + (cb + 1) * ED);
    const float4* w2 = (const float4*)(wrow + (cb + 2) * ED);
    const float4* w3 = (const float4*)(wrow + (cb + 3) * ED);
    float z0 = xs4.x + xd4.x + dot4(ea4[0], w0[0]) + dot4(ea4[1], w0[1]) +
               dot4(ea4[2], w0[2]) + dot4(ea4[3], w0[3]);
    float z1 = xs4.y + xd4.y + dot4(ea4[0], w1[0]) + dot4(ea4[1], w1[1]) +
               dot4(ea4[2], w1[2]) + dot4(ea4[3], w1[3]);
    float z2 = xs4.z + xd4.z + dot4(ea4[0], w2[0]) + dot4(ea4[1], w2[1]) +
               dot4(ea4[2], w2[2]) + dot4(ea4[3], w2[3]);
    float z3 = xs4.w + xd4.w + dot4(ea4[0], w3[0]) + dot4(ea4[1], w3[1]) +
               dot4(ea4[2], w3[2]) + dot4(ea4[3], w3[3]);
    z0 *= (z0 > 0.f) ? 1.0f : NEG;
    z1 *= (z1 > 0.f) ? 1.0f : NEG;
    z2 *= (z2 > 0.f) ? 1.0f : NEG;
    z3 *= (z3 > 0.f) ? 1.0f : NEG;
    float4 a4 = *(const float4*)(arow + cb);
    sc += a4.x * z0 + a4.y * z1 + a4.z * z2 + a4.w * z3;
  }
  sc = fminf(fmaxf(sc, -60.f), 60.f);  // clamp never binds for sane inputs
  wP[(size_t)h * EFP + p] = __expf(sc);
}

// ---- aggregation: block per node, wave per head; single pass (no max/exp) --
__global__ __launch_bounds__(320) void k_agg(
    const int* __restrict__ csr_src, const int* __restrict__ rowptr,
    const float* __restrict__ wP, const float* __restrict__ xl,
    const float* __restrict__ bias, float* __restrict__ out) {
  __shared__ float s_v[NH][CD];
  int h = threadIdx.x >> 6, lane = threadIdx.x & 63;
  int d = blockIdx.x;
  int b = rowptr[d], n = rowptr[d + 1] - b;
  const float* sp = wP + (size_t)h * EFP;
  const float* xlh = xl + h * CD + lane;
  // self loop init
  float dn = sp[NE + d];
  float acc = dn * xlh[(size_t)d * HC];
  // edge loop, unroll 4 (uniform w addrs -> scalar loads)
  int p = b, pe = b + n;
  for (; p + 4 <= pe; p += 4) {
    int s0 = csr_src[p], s1 = csr_src[p + 1], s2 = csr_src[p + 2], s3 = csr_src[p + 3];
    float w0 = sp[p], w1 = sp[p + 1], w2 = sp[p + 2], w3 = sp[p + 3];
    float x0 = xlh[(size_t)s0 * HC];
    float x1 = xlh[(size_t)s1 * HC];
    float x2 = xlh[(size_t)s2 * HC];
    float x3 = xlh[(size_t)s3 * HC];
    dn += (w0 + w1) + (w2 + w3);
    acc += w0 * x0 + w1 * x1 + w2 * x2 + w3 * x3;
  }
  for (; p < pe; p++) {
    int s0 = csr_src[p];
    float w0 = sp[p];
    dn += w0;
    acc += w0 * xlh[(size_t)s0 * HC];
  }
  s_v[h][lane] = acc / dn;
  __syncthreads();
  if (h == 0) {
    float v = s_v[0][lane] + s_v[1][lane] + s_v[2][lane] + s_v[3][lane] + s_v[4][lane];
    v = v * (1.0f / NH) + bias[lane];
    v = v > 0.f ? v : expm1f(v);
    out[(size_t)d * CD + lane] = v;
  }
}

extern "C" void kernel_launch(void* const* d_in, const int* in_sizes, int n_in,
                              void* d_out, int out_size, void* d_ws, size_t ws_size,
                              hipStream_t stream) {
  const float* x = (const float*)d_in[0];
  const int* ei = (const int*)d_in[1];      // [2, NE]: src row then dst row
  const float* eattr = (const float*)d_in[2];

  char* w = (char*)d_ws;
  int* degi      = (int*)w;                 w += NN * 4;
  int* cursor    = (int*)w;                 w += NN * 4;
  int* rowptr    = (int*)w;                 w += (NN + 1) * 4;
  int* csr_eid   = (int*)w;                 w += NE * 4;
  int* csr_src   = (int*)w;                 w += NE * 4;
  int* csr_dst   = (int*)w;                 w += NE * 4;
  float* loop_attr = (float*)w;             w += (size_t)NN * ED * 4;
  float* ea_csr  = (float*)w;               w += (size_t)NE * ED * 4;
  float* xl      = (float*)w;               w += (size_t)NN * HC * 4;
  float* wPbuf   = (float*)w;               w += (size_t)NH * EFP * 4;
  float* WeT     = (float*)w;               w += (size_t)ED * HC * 4;
  float* hbuf    = (float*)w;               w += (size_t)NN * CD * 4;

  // graph structure + permuted edge attrs (layer-invariant)
  hipMemsetAsync(degi, 0, NN * 4, stream);
  hipMemsetAsync(cursor, 0, NN * 4, stream);
  k_count<<<(NE + 255) / 256, 256, 0, stream>>>(ei + NE, degi);
  k_scan<<<1, 1024, 0, stream>>>(degi, rowptr);
  k_fill<<<(NE + 255) / 256, 256, 0, stream>>>(ei, rowptr, cursor, csr_eid, csr_src, csr_dst);
  k_loopattr<<<(NN + 3) / 4, 256, 0, stream>>>(csr_eid, rowptr, eattr, loop_attr);
  k_eacsr<<<(NE * 4 + 255) / 256, 256, 0, stream>>>(csr_eid, eattr, ea_csr);

  for (int l = 0; l < 3; l++) {
    const float* Wl  = (const float*)d_in[3 + 5 * l];
    const float* bl  = (const float*)d_in[4 + 5 * l];
    const float* We  = (const float*)d_in[5 + 5 * l];
    const float* att = (const float*)d_in[6 + 5 * l];
    const float* b   = (const float*)d_in[7 + 5 * l];

    k_wet<<<(ED * HC + 255) / 256, 256, 0, stream>>>(We, WeT);
    if (l == 0) k_xl<ND><<<NN / 8, 320, 0, stream>>>(x, Wl, bl, xl);
    else        k_xl<CD><<<NN / 8, 320, 0, stream>>>(hbuf, Wl, bl, xl);

    dim3 gs(8 * SB, NH);
    k_score<<<gs, 256, 0, stream>>>(csr_src, csr_dst, ea_csr, loop_attr,
                                    xl, WeT, att, wPbuf);

    float* dst_out = (l < 2) ? hbuf : (float*)d_out;
    k_agg<<<NN, 320, 0, stream>>>(csr_src, rowptr, wPbuf, xl, b, dst_out);
  }
}